// Round 4
// baseline (54.794 us; speedup 1.0000x reference)
//
#include <hip/hip_runtime.h>

typedef float f32x4 __attribute__((ext_vector_type(4)));

// ---- order-preserving float<->uint encoding for atomicMax on floats ----
__device__ __forceinline__ unsigned enc_f32(float f) {
    unsigned b = __float_as_uint(f);
    return (b & 0x80000000u) ? ~b : (b | 0x80000000u);
}
__device__ __forceinline__ float dec_f32(unsigned u) {
    unsigned b = (u & 0x80000000u) ? (u & 0x7FFFFFFFu) : ~u;
    return __uint_as_float(b);
}

// ---- pass 1: max of tx -> ws[0], max of ty -> ws[1], one dispatch ----
__global__ void table_max2_kernel(const float* __restrict__ tx,
                                  const float* __restrict__ ty,
                                  int n, unsigned* __restrict__ ws) {
    const int half = gridDim.x >> 1;
    const bool isx = (int)blockIdx.x < half;
    const float* t = isx ? tx : ty;
    unsigned* slot = ws + (isx ? 0 : 1);
    const int b = isx ? blockIdx.x : blockIdx.x - half;
    const int stride = half * blockDim.x;
    float m = -INFINITY;
    for (int i = b * blockDim.x + threadIdx.x; i < n; i += stride)
        m = fmaxf(m, t[i]);
    #pragma unroll
    for (int off = 32; off > 0; off >>= 1)
        m = fmaxf(m, __shfl_down(m, off, 64));
    __shared__ float sm[4];
    int lane = threadIdx.x & 63, wid = threadIdx.x >> 6;
    if (lane == 0) sm[wid] = m;
    __syncthreads();
    if (threadIdx.x == 0) {
        float mm = fmaxf(fmaxf(sm[0], sm[1]), fmaxf(sm[2], sm[3]));
        atomicMax(slot, enc_f32(mm));
    }
}

// ---- pass 2: build pair-summed combined tables (each [rows][64] f32) ----
__global__ void build_kernel(const float* __restrict__ fixedt,
                             const float* __restrict__ tx,
                             const float* __restrict__ ty,
                             const unsigned* __restrict__ ws,
                             float* __restrict__ cx, float* __restrict__ cy,
                             int total /* rows*64 */) {
    const float sx = 0.1f / dec_f32(ws[0]);
    const float sy = 0.1f / dec_f32(ws[1]);
    const int stride = gridDim.x * blockDim.x;
    for (int i = blockIdx.x * blockDim.x + threadIdx.x; i < total; i += stride) {
        const int p = i >> 6, j = i & 63;
        const float2 fv = *reinterpret_cast<const float2*>(fixedt + p * 128 + 2 * j);
        const float2 xv = *reinterpret_cast<const float2*>(tx     + p * 128 + 2 * j);
        const float2 yv = *reinterpret_cast<const float2*>(ty     + p * 128 + 2 * j);
        const float f = fv.x + fv.y;
        cx[i] = sx * (xv.x + xv.y) + f;
        cy[i] = sy * (yv.x + yv.y) + f;
    }
}

// ---- pass 3: float4 gather, loop-invariant lane state + 4-way unrolled MLP ----
// float4 index i: row = i>>5, q = i&31 (invariant: stride % 32 == 0).
__global__ void gather_kernel(const int* __restrict__ pos,
                              const f32x4* __restrict__ cx,
                              const f32x4* __restrict__ cy,
                              f32x4* __restrict__ out, int total4) {
    const int stride = gridDim.x * blockDim.x;      // multiple of 32
    const int i0 = blockIdx.x * blockDim.x + threadIdx.x;
    // loop-invariant per-lane state
    const int  q    = i0 & 31;
    const bool isx  = (q < 16);
    const f32x4* __restrict__ tab = isx ? cx : cy;
    const int  j    = isx ? q : q - 16;
    const int  poff = isx ? 0 : 1;
    const int  rowstep = stride >> 5;

    int i = i0;
    int row = i0 >> 5;
    // 4-way unroll: 4 independent pos-load -> table-load chains, then 4 stores
    for (; i + 3 * stride < total4; i += 4 * stride, row += 4 * rowstep) {
        int p0 = pos[2 * (row + 0 * rowstep) + poff];
        int p1 = pos[2 * (row + 1 * rowstep) + poff];
        int p2 = pos[2 * (row + 2 * rowstep) + poff];
        int p3 = pos[2 * (row + 3 * rowstep) + poff];
        p0 = (p0 < 0) ? 1 : p0;  p1 = (p1 < 0) ? 1 : p1;
        p2 = (p2 < 0) ? 1 : p2;  p3 = (p3 < 0) ? 1 : p3;
        const f32x4 v0 = tab[p0 * 16 + j];
        const f32x4 v1 = tab[p1 * 16 + j];
        const f32x4 v2 = tab[p2 * 16 + j];
        const f32x4 v3 = tab[p3 * 16 + j];
        __builtin_nontemporal_store(v0, &out[i + 0 * stride]);
        __builtin_nontemporal_store(v1, &out[i + 1 * stride]);
        __builtin_nontemporal_store(v2, &out[i + 2 * stride]);
        __builtin_nontemporal_store(v3, &out[i + 3 * stride]);
    }
    for (; i < total4; i += stride, row += rowstep) {
        int p = pos[2 * row + poff];
        if (p < 0) p = 1;
        __builtin_nontemporal_store(tab[p * 16 + j], &out[i]);
    }
}

// ---- fallback (small ws): direct fused gather, float4 ----
__global__ void direct_kernel(const int* __restrict__ pos,
                              const float* __restrict__ fixedt,
                              const float* __restrict__ tx,
                              const float* __restrict__ ty,
                              const unsigned* __restrict__ ws,
                              f32x4* __restrict__ out, int total4) {
    const float sx = 0.1f / dec_f32(ws[0]);
    const float sy = 0.1f / dec_f32(ws[1]);
    const int stride = gridDim.x * blockDim.x;
    for (int i = blockIdx.x * blockDim.x + threadIdx.x; i < total4; i += stride) {
        const int q   = i & 31;
        const int row = i >> 5;
        const bool isx = (q < 16);
        int p = pos[2 * row + (isx ? 0 : 1)];
        if (p < 0) p = 1;
        const float s = isx ? sx : sy;
        const float* tab = isx ? tx : ty;
        const int j8 = (isx ? q : q - 16) * 8;
        const float4 t0 = *reinterpret_cast<const float4*>(tab + p * 128 + j8);
        const float4 t1 = *reinterpret_cast<const float4*>(tab + p * 128 + j8 + 4);
        const float4 f0 = *reinterpret_cast<const float4*>(fixedt + p * 128 + j8);
        const float4 f1 = *reinterpret_cast<const float4*>(fixedt + p * 128 + j8 + 4);
        f32x4 v;
        v.x = s * (t0.x + t0.y) + (f0.x + f0.y);
        v.y = s * (t0.z + t0.w) + (f0.z + f0.w);
        v.z = s * (t1.x + t1.y) + (f1.x + f1.y);
        v.w = s * (t1.z + t1.w) + (f1.z + f1.w);
        __builtin_nontemporal_store(v, &out[i]);
    }
}

extern "C" void kernel_launch(void* const* d_in, const int* in_sizes, int n_in,
                              void* d_out, int out_size, void* d_ws, size_t ws_size,
                              hipStream_t stream) {
    const int*   pos    = (const int*)  d_in[0];   // [16,512,32,2]
    const float* fixedt = (const float*)d_in[1];   // [table_len,128]
    const float* tx     = (const float*)d_in[2];
    const float* ty     = (const float*)d_in[3];
    float* out = (float*)d_out;
    unsigned* ws = (unsigned*)d_ws;

    const int n_table  = in_sizes[2];              // table_len * 128
    const int rows     = n_table >> 7;             // table_len
    const int total    = out_size;                 // 33.5M
    const int total4   = total >> 2;

    const size_t c_off_f = 64;                              // floats
    const size_t need = 256 + (size_t)rows * 64 * 4 * 2;    // bytes

    (void)hipMemsetAsync(ws, 0, 2 * sizeof(unsigned), stream);
    table_max2_kernel<<<1024, 256, 0, stream>>>(tx, ty, n_table, ws);

    if (ws_size >= need) {
        float* cx = (float*)ws + c_off_f;
        float* cy = cx + (size_t)rows * 64;
        int btot = rows * 64;
        build_kernel<<<(btot + 255) / 256, 256, 0, stream>>>(fixedt, tx, ty, ws, cx, cy, btot);
        gather_kernel<<<2048, 256, 0, stream>>>(pos, (const f32x4*)cx, (const f32x4*)cy,
                                                (f32x4*)out, total4);
    } else {
        direct_kernel<<<2048, 256, 0, stream>>>(pos, fixedt, tx, ty, ws,
                                                (f32x4*)out, total4);
    }
}

// Round 5
// 42.322 us; speedup vs baseline: 1.2947x; 1.2947x over previous
//
#include <hip/hip_runtime.h>

typedef float f32x4 __attribute__((ext_vector_type(4)));

#define NB 512   // partial-max blocks per table

// ---- pass 1: per-block partial maxes (no atomics, no memset needed) ----
// grid = 2*NB blocks: first NB -> tx partials, next NB -> ty partials.
__global__ void table_max_partial(const float* __restrict__ tx,
                                  const float* __restrict__ ty,
                                  int n, float* __restrict__ px,
                                  float* __restrict__ py) {
    const bool isx = (int)blockIdx.x < NB;
    const float* t = isx ? tx : ty;
    float* dst = isx ? px : py;
    const int b = isx ? blockIdx.x : blockIdx.x - NB;
    const int stride = NB * blockDim.x;
    float m = -INFINITY;
    for (int i = b * blockDim.x + threadIdx.x; i < n; i += stride)
        m = fmaxf(m, t[i]);
    #pragma unroll
    for (int off = 32; off > 0; off >>= 1)
        m = fmaxf(m, __shfl_down(m, off, 64));
    __shared__ float sm[4];
    int lane = threadIdx.x & 63, wid = threadIdx.x >> 6;
    if (lane == 0) sm[wid] = m;
    __syncthreads();
    if (threadIdx.x == 0)
        dst[b] = fmaxf(fmaxf(sm[0], sm[1]), fmaxf(sm[2], sm[3]));
}

// ---- block-wide reduce of the two partial arrays -> (sx, sy) ----
__device__ void reduce_scales(const float* __restrict__ px,
                              const float* __restrict__ py,
                              float& sx, float& sy) {
    // 256 threads, NB=512 partials each table: 2 elems/thread
    float mx = fmaxf(px[threadIdx.x], px[threadIdx.x + 256]);
    float my = fmaxf(py[threadIdx.x], py[threadIdx.x + 256]);
    #pragma unroll
    for (int off = 32; off > 0; off >>= 1) {
        mx = fmaxf(mx, __shfl_down(mx, off, 64));
        my = fmaxf(my, __shfl_down(my, off, 64));
    }
    __shared__ float smx[4], smy[4];
    int lane = threadIdx.x & 63, wid = threadIdx.x >> 6;
    if (lane == 0) { smx[wid] = mx; smy[wid] = my; }
    __syncthreads();
    const float fmx = fmaxf(fmaxf(smx[0], smx[1]), fmaxf(smx[2], smx[3]));
    const float fmy = fmaxf(fmaxf(smy[0], smy[1]), fmaxf(smy[2], smy[3]));
    sx = 0.1f / fmx;
    sy = 0.1f / fmy;
}

// ---- pass 2: build pair-summed combined tables (each [rows][64] f32) ----
__global__ void build_kernel(const float* __restrict__ fixedt,
                             const float* __restrict__ tx,
                             const float* __restrict__ ty,
                             const float* __restrict__ px,
                             const float* __restrict__ py,
                             float* __restrict__ cx, float* __restrict__ cy,
                             int total /* rows*64 */) {
    float sx, sy;
    reduce_scales(px, py, sx, sy);
    const int stride = gridDim.x * blockDim.x;
    for (int i = blockIdx.x * blockDim.x + threadIdx.x; i < total; i += stride) {
        const int p = i >> 6, j = i & 63;
        const float2 fv = *reinterpret_cast<const float2*>(fixedt + p * 128 + 2 * j);
        const float2 xv = *reinterpret_cast<const float2*>(tx     + p * 128 + 2 * j);
        const float2 yv = *reinterpret_cast<const float2*>(ty     + p * 128 + 2 * j);
        const float f = fv.x + fv.y;
        cx[i] = sx * (xv.x + xv.y) + f;
        cy[i] = sy * (yv.x + yv.y) + f;
    }
}

// ---- pass 3: pure float4 gather, plain stores (L2 write-allocate) ----
// float4 index i: row = i>>5, q = i&31 (stride % 32 == 0 -> q invariant).
__global__ void gather_kernel(const int* __restrict__ pos,
                              const f32x4* __restrict__ cx,
                              const f32x4* __restrict__ cy,
                              f32x4* __restrict__ out, int total4) {
    const int stride = gridDim.x * blockDim.x;      // multiple of 32
    const int i0 = blockIdx.x * blockDim.x + threadIdx.x;
    const int  q    = i0 & 31;
    const bool isx  = (q < 16);
    const f32x4* __restrict__ tab = isx ? cx : cy;
    const int  j    = isx ? q : q - 16;
    const int  poff = isx ? 0 : 1;
    const int  rowstep = stride >> 5;

    int row = i0 >> 5;
    for (int i = i0; i < total4; i += stride, row += rowstep) {
        int p = pos[2 * row + poff];                // 16-lane-uniform broadcast
        if (p < 0) p = 1;
        out[i] = tab[p * 16 + j];
    }
}

// ---- fallback (small ws): direct fused gather ----
__global__ void direct_kernel(const int* __restrict__ pos,
                              const float* __restrict__ fixedt,
                              const float* __restrict__ tx,
                              const float* __restrict__ ty,
                              const float* __restrict__ px,
                              const float* __restrict__ py,
                              f32x4* __restrict__ out, int total4) {
    float sx, sy;
    reduce_scales(px, py, sx, sy);
    const int stride = gridDim.x * blockDim.x;
    for (int i = blockIdx.x * blockDim.x + threadIdx.x; i < total4; i += stride) {
        const int q   = i & 31;
        const int row = i >> 5;
        const bool isx = (q < 16);
        int p = pos[2 * row + (isx ? 0 : 1)];
        if (p < 0) p = 1;
        const float s = isx ? sx : sy;
        const float* tab = isx ? tx : ty;
        const int j8 = (isx ? q : q - 16) * 8;
        const float4 t0 = *reinterpret_cast<const float4*>(tab + p * 128 + j8);
        const float4 t1 = *reinterpret_cast<const float4*>(tab + p * 128 + j8 + 4);
        const float4 f0 = *reinterpret_cast<const float4*>(fixedt + p * 128 + j8);
        const float4 f1 = *reinterpret_cast<const float4*>(fixedt + p * 128 + j8 + 4);
        f32x4 v;
        v.x = s * (t0.x + t0.y) + (f0.x + f0.y);
        v.y = s * (t0.z + t0.w) + (f0.z + f0.w);
        v.z = s * (t1.x + t1.y) + (f1.x + f1.y);
        v.w = s * (t1.z + t1.w) + (f1.z + f1.w);
        out[i] = v;
    }
}

extern "C" void kernel_launch(void* const* d_in, const int* in_sizes, int n_in,
                              void* d_out, int out_size, void* d_ws, size_t ws_size,
                              hipStream_t stream) {
    const int*   pos    = (const int*)  d_in[0];   // [16,512,32,2]
    const float* fixedt = (const float*)d_in[1];   // [table_len,128]
    const float* tx     = (const float*)d_in[2];
    const float* ty     = (const float*)d_in[3];
    float* out = (float*)d_out;

    const int n_table  = in_sizes[2];              // table_len * 128
    const int rows     = n_table >> 7;             // table_len
    const int total4   = out_size >> 2;

    // ws layout: px[NB], py[NB], then cx[rows*64], cy[rows*64]
    float* px = (float*)d_ws;
    float* py = px + NB;
    float* cx = py + NB;
    float* cy = cx + (size_t)rows * 64;
    const size_t need = (2 * NB + (size_t)rows * 64 * 2) * 4;

    table_max_partial<<<2 * NB, 256, 0, stream>>>(tx, ty, n_table, px, py);

    if (ws_size >= need) {
        int btot = rows * 64;
        build_kernel<<<(btot + 255) / 256, 256, 0, stream>>>(fixedt, tx, ty, px, py,
                                                             cx, cy, btot);
        gather_kernel<<<2048, 256, 0, stream>>>(pos, (const f32x4*)cx, (const f32x4*)cy,
                                                (f32x4*)out, total4);
    } else {
        direct_kernel<<<2048, 256, 0, stream>>>(pos, fixedt, tx, ty, px, py,
                                                (f32x4*)out, total4);
    }
}